// Round 14
// baseline (2134.330 us; speedup 1.0000x reference)
//
#include <hip/hip_runtime.h>
#include <math.h>

#define NHEADS 12
#define DHEAD  64
#define SEQL   512
#define HID    768
#define IMID   3072
#define NTOK   4096
#define NLAY   12
#define QKVW   2304

typedef __attribute__((ext_vector_type(8))) short short8;
typedef __attribute__((ext_vector_type(4))) float f32x4;

__device__ __forceinline__ short f2b(float f) {
    union { float f; unsigned u; } v; v.f = f;
    unsigned r = (v.u + 0x7fffu + ((v.u >> 16) & 1u)) >> 16;
    return (short)r;
}
__device__ __forceinline__ float b2f(short h) {
    union { unsigned u; float f; } v; v.u = ((unsigned)(unsigned short)h) << 16;
    return v.f;
}
__device__ __forceinline__ void mfma16(f32x4& c, short8 a, short8 b) {
    asm volatile("v_mfma_f32_16x16x32_bf16 %0, %1, %2, %0" : "+v"(c) : "v"(a), "v"(b));
}
__device__ __forceinline__ void accfence() {
    __builtin_amdgcn_sched_barrier(0);
    asm volatile("s_nop 7\ns_nop 7\ns_nop 7\ns_nop 7");
    __builtin_amdgcn_sched_barrier(0);
}
__device__ __forceinline__ void gload_lds16(const void* g, void* l) {
    __builtin_amdgcn_global_load_lds(
        (const __attribute__((address_space(1))) unsigned int*)g,
        (__attribute__((address_space(3))) unsigned int*)l, 16, 0, 0);
}
// exact-GELU via A&S 7.1.26 erf approx (|eps|<1.5e-7, << bf16 ulp)
__device__ __forceinline__ float gelu_f(float v) {
    float x = v * 0.70710678118f;
    float ax = fabsf(x);
    float t = 1.0f / (1.0f + 0.3275911f * ax);
    float p = ((((1.061405429f * t - 1.453152027f) * t) + 1.421413741f) * t
               - 0.284496736f) * t + 0.254829592f;
    float e = p * t * __expf(-x * x);
    float er = 1.0f - e;
    er = x < 0.f ? -er : er;
    return 0.5f * v * (1.0f + er);
}

// ---------------- weight convert+transpose: W f32 [K,N] -> WT bf16 [N,K] (x scale) ----------------
__global__ __launch_bounds__(256) void wconv_k(
    const float* __restrict__ src, short* __restrict__ dst,
    int K, int N, size_t dlsz, int rowStart, float scale)
{
    __shared__ short t[64][72];
    src += (size_t)blockIdx.z * K * N;
    dst += (size_t)blockIdx.z * dlsz;
    const int k0 = blockIdx.x * 64, n0 = blockIdx.y * 64;
    const int kr = threadIdx.x >> 2, q = threadIdx.x & 3;
    const float* s = src + (size_t)(k0 + kr) * N + n0 + q * 16;
#pragma unroll
    for (int j = 0; j < 16; j += 4) {
        float4 v = *reinterpret_cast<const float4*>(s + j);
        t[q * 16 + j + 0][kr] = f2b(v.x * scale);
        t[q * 16 + j + 1][kr] = f2b(v.y * scale);
        t[q * 16 + j + 2][kr] = f2b(v.z * scale);
        t[q * 16 + j + 3][kr] = f2b(v.w * scale);
    }
    __syncthreads();
    const int r = threadIdx.x >> 2;
    short* d = dst + (size_t)(rowStart + n0 + r) * K + k0 + q * 16;
    *reinterpret_cast<short8*>(d)     = *reinterpret_cast<short8*>(&t[r][q * 16]);
    *reinterpret_cast<short8*>(d + 8) = *reinterpret_cast<short8*>(&t[r][q * 16 + 8]);
}

__global__ __launch_bounds__(256) void bpack_k(
    const float* __restrict__ bq, const float* __restrict__ bk,
    const float* __restrict__ bv, float* __restrict__ dst)
{
    int i = blockIdx.x * 256 + threadIdx.x;
    if (i >= NLAY * QKVW) return;
    int l = i / QKVW, c = i % QKVW;
    float v = c < 768 ? 0.125f * bq[l * 768 + c]
            : c < 1536 ? bk[l * 768 + c - 768] : bv[l * 768 + c - 1536];
    dst[i] = v;
}

// ---------------- embeddings + LN ----------------
__global__ __launch_bounds__(256) void embed_ln_k(
    const int* __restrict__ ids, const int* __restrict__ tti,
    const float* __restrict__ tokE, const float* __restrict__ posE,
    const float* __restrict__ typE, const float* __restrict__ g,
    const float* __restrict__ bb, float* __restrict__ x, short* __restrict__ xb)
{
    __shared__ float red[8];
    const int t = blockIdx.x, s = t & (SEQL - 1);
    const int id = ids[t], ty = tti[t];
    float v[3], sum = 0.f, sq = 0.f;
#pragma unroll
    for (int i = 0; i < 3; ++i) {
        const int c = threadIdx.x + 256 * i;
        float e = tokE[(size_t)id * HID + c] + typE[(size_t)ty * HID + c]
                + posE[(size_t)s * HID + c];
        v[i] = e; sum += e; sq += e * e;
    }
#pragma unroll
    for (int d = 1; d < 64; d <<= 1) { sum += __shfl_xor(sum, d); sq += __shfl_xor(sq, d); }
    const int lane = threadIdx.x & 63, w = threadIdx.x >> 6;
    if (lane == 0) { red[w] = sum; red[4 + w] = sq; }
    __syncthreads();
    sum = red[0] + red[1] + red[2] + red[3];
    sq  = red[4] + red[5] + red[6] + red[7];
    const float mu = sum * (1.0f / 768.0f);
    const float var = sq * (1.0f / 768.0f) - mu * mu;
    const float rstd = rsqrtf(var + 1e-3f);
#pragma unroll
    for (int i = 0; i < 3; ++i) {
        const int c = threadIdx.x + 256 * i;
        float yv = (v[i] - mu) * rstd * g[c] + bb[c];
        if (x) x[(size_t)t * HID + c] = yv;
        xb[(size_t)t * HID + c] = f2b(yv);
    }
}

// ---------------- residual add + LN (legacy, fallback path) ----------------
__global__ __launch_bounds__(256) void add_ln_k(
    const float* __restrict__ y, const float* __restrict__ res,
    const float* __restrict__ g, const float* __restrict__ bb,
    float* __restrict__ xout, short* __restrict__ bout, float* __restrict__ fout)
{
    __shared__ float red[8];
    const int t = blockIdx.x;
    float v[3], sum = 0.f, sq = 0.f;
#pragma unroll
    for (int i = 0; i < 3; ++i) {
        const int c = threadIdx.x + 256 * i;
        float e = y[(size_t)t * HID + c] + res[(size_t)t * HID + c];
        v[i] = e; sum += e; sq += e * e;
    }
#pragma unroll
    for (int d = 1; d < 64; d <<= 1) { sum += __shfl_xor(sum, d); sq += __shfl_xor(sq, d); }
    const int lane = threadIdx.x & 63, w = threadIdx.x >> 6;
    if (lane == 0) { red[w] = sum; red[4 + w] = sq; }
    __syncthreads();
    sum = red[0] + red[1] + red[2] + red[3];
    sq  = red[4] + red[5] + red[6] + red[7];
    const float mu = sum * (1.0f / 768.0f);
    const float var = sq * (1.0f / 768.0f) - mu * mu;
    const float rstd = rsqrtf(var + 1e-3f);
#pragma unroll
    for (int i = 0; i < 3; ++i) {
        const int c = threadIdx.x + 256 * i;
        float yv = (v[i] - mu) * rstd * g[c] + bb[c];
        xout[(size_t)t * HID + c] = yv;
        bout[(size_t)t * HID + c] = f2b(yv);
        if (fout) fout[(size_t)t * HID + c] = yv;
    }
}

// ---------------- split-K(2) bf16 partials + bf16 residual + LN -> bf16 stream ----------------
__global__ __launch_bounds__(256) void add_ln_red_k(
    const short* __restrict__ p0, const short* __restrict__ p1,
    const short* __restrict__ res, const float* __restrict__ g,
    const float* __restrict__ bb, short* __restrict__ bout, float* __restrict__ fout)
{
    __shared__ float red[8];
    const int t = blockIdx.x;
    float v[3], sum = 0.f, sq = 0.f;
#pragma unroll
    for (int i = 0; i < 3; ++i) {
        const int c = threadIdx.x + 256 * i;
        const size_t o = (size_t)t * HID + c;
        float e = b2f(p0[o]) + b2f(p1[o]) + b2f(res[o]);
        v[i] = e; sum += e; sq += e * e;
    }
#pragma unroll
    for (int d = 1; d < 64; d <<= 1) { sum += __shfl_xor(sum, d); sq += __shfl_xor(sq, d); }
    const int lane = threadIdx.x & 63, w = threadIdx.x >> 6;
    if (lane == 0) { red[w] = sum; red[4 + w] = sq; }
    __syncthreads();
    sum = red[0] + red[1] + red[2] + red[3];
    sq  = red[4] + red[5] + red[6] + red[7];
    const float mu = sum * (1.0f / 768.0f);
    const float var = sq * (1.0f / 768.0f) - mu * mu;
    const float rstd = rsqrtf(var + 1e-3f);
#pragma unroll
    for (int i = 0; i < 3; ++i) {
        const int c = threadIdx.x + 256 * i;
        float yv = (v[i] - mu) * rstd * g[c] + bb[c];
        bout[(size_t)t * HID + c] = f2b(yv);
        if (fout) fout[(size_t)t * HID + c] = yv;
    }
}

// ---------------- split-K(4) bf16 partials + bf16 residual + LN -> bf16 stream ----------------
__global__ __launch_bounds__(256) void add_ln_red4_k(
    const short* __restrict__ p0, const short* __restrict__ p1,
    const short* __restrict__ p2, const short* __restrict__ p3,
    const short* __restrict__ res, const float* __restrict__ g,
    const float* __restrict__ bb, short* __restrict__ bout, float* __restrict__ fout)
{
    __shared__ float red[8];
    const int t = blockIdx.x;
    float v[3], sum = 0.f, sq = 0.f;
#pragma unroll
    for (int i = 0; i < 3; ++i) {
        const int c = threadIdx.x + 256 * i;
        const size_t o = (size_t)t * HID + c;
        float e = (b2f(p0[o]) + b2f(p1[o])) + (b2f(p2[o]) + b2f(p3[o])) + b2f(res[o]);
        v[i] = e; sum += e; sq += e * e;
    }
#pragma unroll
    for (int d = 1; d < 64; d <<= 1) { sum += __shfl_xor(sum, d); sq += __shfl_xor(sq, d); }
    const int lane = threadIdx.x & 63, w = threadIdx.x >> 6;
    if (lane == 0) { red[w] = sum; red[4 + w] = sq; }
    __syncthreads();
    sum = red[0] + red[1] + red[2] + red[3];
    sq  = red[4] + red[5] + red[6] + red[7];
    const float mu = sum * (1.0f / 768.0f);
    const float var = sq * (1.0f / 768.0f) - mu * mu;
    const float rstd = rsqrtf(var + 1e-3f);
#pragma unroll
    for (int i = 0; i < 3; ++i) {
        const int c = threadIdx.x + 256 * i;
        float yv = (v[i] - mu) * rstd * g[c] + bb[c];
        bout[(size_t)t * HID + c] = f2b(yv);
        if (fout) fout[(size_t)t * HID + c] = yv;
    }
}

// ---------------- pipelined GEMM, 8-wave blocks: C[4096,N] = A[M,K] @ WT[N,K]^T ----------------
// EPI 0 = f32+bias; 1 = GELU bf16; 5 = QKV (Q,K linear; V tiles -> Out2 = vt transposed);
// 6 = split-K bf16 partial, up to 4 chunks -> {Out,Out2,Out3,Out4}[blockIdx.y]
template<int EPI>
__global__ __launch_bounds__(512, 4) void gemm3_k(
    const short* __restrict__ A, const short* __restrict__ Wt,
    const float* __restrict__ bias, void* __restrict__ Out, int K, int N, int kChunk,
    void* __restrict__ Out2, void* __restrict__ Out3, void* __restrict__ Out4)
{
    __shared__ short sA[3][128 * 32];
    __shared__ short sB[3][128 * 32];
    const int tid = threadIdx.x;
    const int lane = tid & 63, wave = tid >> 6;
    const int wm = wave >> 1, wn = wave & 1;
    const int rl = lane & 15, hi = lane >> 4;

    const int nb = gridDim.x, bid = blockIdx.x;
    const int id = (bid & 7) * (nb >> 3) + (bid >> 3);
    const int m0 = (id & 31) * 128, n0 = (id >> 5) * 128;
    const int kBeg = blockIdx.y * kChunk;

    f32x4 acc[2][4];
#pragma unroll
    for (int i = 0; i < 2; ++i)
#pragma unroll
        for (int j = 0; j < 4; ++j)
            acc[i][j] = (f32x4){0.f, 0.f, 0.f, 0.f};

    auto stage = [&](int buf, int k0) {
        const int gb = wave * 64;
        const int gid = gb + lane;
        const int row = gid >> 2, sg = gid & 3;
        const int ksw = (sg ^ ((row >> 1) & 3)) << 3;
        gload_lds16(&A[(size_t)(m0 + row) * K + k0 + ksw], &sA[buf][gb * 8]);
        gload_lds16(&Wt[(size_t)(n0 + row) * K + k0 + ksw], &sB[buf][gb * 8]);
    };

    const int nIter = kChunk >> 5;
    stage(0, kBeg);
    if (nIter > 1) stage(1, kBeg + 32);
    for (int t = 0; t < nIter; ++t) {
        const int cur = t % 3;
        if (t + 2 < nIter) {
            stage((t + 2) % 3, kBeg + (t + 2) * 32);
            __builtin_amdgcn_sched_barrier(0);
            asm volatile("s_waitcnt vmcnt(4)" ::: "memory");
        } else if (t + 1 < nIter) {
            __builtin_amdgcn_sched_barrier(0);
            asm volatile("s_waitcnt vmcnt(2)" ::: "memory");
        } else {
            __builtin_amdgcn_sched_barrier(0);
            asm volatile("s_waitcnt vmcnt(0)" ::: "memory");
        }
        __builtin_amdgcn_s_barrier();
        __builtin_amdgcn_sched_barrier(0);

        short8 af[2], bfr[4];
#pragma unroll
        for (int f = 0; f < 2; ++f) {
            const int ra = wm * 32 + f * 16 + rl;
            af[f] = *reinterpret_cast<const short8*>(&sA[cur][ra * 32 + ((hi ^ ((ra >> 1) & 3)) << 3)]);
        }
#pragma unroll
        for (int j = 0; j < 4; ++j) {
            const int rb = wn * 64 + j * 16 + rl;
            bfr[j] = *reinterpret_cast<const short8*>(&sB[cur][rb * 32 + ((hi ^ ((rb >> 1) & 3)) << 3)]);
        }
#pragma unroll
        for (int i = 0; i < 2; ++i)
#pragma unroll
            for (int j = 0; j < 4; ++j)
                mfma16(acc[i][j], af[i], bfr[j]);

        asm volatile("s_waitcnt lgkmcnt(0)" ::: "memory");
        __builtin_amdgcn_sched_barrier(0);
        __builtin_amdgcn_s_barrier();
    }
    accfence();

    if (EPI == 5 && n0 >= 1536) {
        short* tl = (short*)&sA[0][0];
        const int b = m0 >> 9, s0 = m0 & 511;
        const int vbase = n0 - 1536;
        const int c = tid >> 2, rq = (tid & 3) << 4;
        const int vcol = vbase + c;
        short* dstRow = (short*)Out2 +
            (((size_t)(b * NHEADS + (vcol >> 6)) * DHEAD + (vcol & 63)) << 9) + s0;
#pragma unroll
        for (int pass = 0; pass < 2; ++pass) {
            if ((wm >> 1) == pass) {
#pragma unroll
                for (int j = 0; j < 4; ++j) {
                    const int cc = wn * 64 + j * 16 + rl;
                    const float bv = bias[n0 + cc];
#pragma unroll
                    for (int i = 0; i < 2; ++i)
#pragma unroll
                        for (int e = 0; e < 4; ++e) {
                            const int r = (wm & 1) * 32 + i * 16 + hi * 4 + e;
                            tl[cc * 68 + r] = f2b(acc[i][j][e] + bv);
                        }
                }
            }
            __builtin_amdgcn_s_barrier();
            *reinterpret_cast<short8*>(dstRow + pass * 64 + rq) =
                *reinterpret_cast<short8*>(&tl[c * 68 + rq]);
            *reinterpret_cast<short8*>(dstRow + pass * 64 + rq + 8) =
                *reinterpret_cast<short8*>(&tl[c * 68 + rq + 8]);
            __builtin_amdgcn_s_barrier();
        }
        return;
    }

    short* skDst = nullptr;
    if (EPI == 6)
        skDst = blockIdx.y == 0 ? (short*)Out
              : blockIdx.y == 1 ? (short*)Out2
              : blockIdx.y == 2 ? (short*)Out3 : (short*)Out4;
#pragma unroll
    for (int j = 0; j < 4; ++j) {
        const int col = n0 + wn * 64 + j * 16 + rl;
        const float bv = (EPI == 6 && blockIdx.y != 0) ? 0.f : bias[col];
#pragma unroll
        for (int i = 0; i < 2; ++i) {
#pragma unroll
            for (int e = 0; e < 4; ++e) {
                const int row = m0 + wm * 32 + i * 16 + hi * 4 + e;
                float v = acc[i][j][e] + bv;
                if (EPI == 0) {
                    ((float*)Out)[(size_t)row * N + col] = v;
                } else if (EPI == 1) {
                    ((short*)Out)[(size_t)row * N + col] = f2b(gelu_f(v));
                } else if (EPI == 6) {
                    skDst[(size_t)row * N + col] = f2b(v);
                } else {
                    ((short*)Out)[(size_t)row * N + col] = f2b(v);
                }
            }
        }
    }
}

// ---------------- legacy GEMM (fallback path): W f32 [K,N] ----------------
template<int EPI>
__global__ __launch_bounds__(256) void gemm_k(
    const short* __restrict__ A, const float* __restrict__ W,
    const float* __restrict__ bias, void* __restrict__ Out, int K, int N)
{
    __shared__ short sA[128 * 40];
    __shared__ short sB[128 * 40];
    const int tid = threadIdx.x;
    const int lane = tid & 63, wave = tid >> 6;
    const int wm = wave >> 1, wn = wave & 1;
    const int m0 = blockIdx.x * 128, n0 = blockIdx.y * 128;
    const int rl = lane & 15, hi = lane >> 4;

    f32x4 acc[4][4];
#pragma unroll
    for (int i = 0; i < 4; ++i)
#pragma unroll
        for (int j = 0; j < 4; ++j)
            acc[i][j] = (f32x4){0.f, 0.f, 0.f, 0.f};

    const int arow = tid >> 2, ac8 = (tid & 3) << 3;
    const int bk0 = tid >> 5, bn4 = (tid & 31) << 2;

    for (int k0 = 0; k0 < K; k0 += 32) {
#pragma unroll
        for (int i = 0; i < 2; ++i) {
            int row = i * 64 + arow;
            short8 v = *reinterpret_cast<const short8*>(&A[(size_t)(m0 + row) * K + k0 + ac8]);
            *reinterpret_cast<short8*>(&sA[row * 40 + ac8]) = v;
        }
#pragma unroll
        for (int p = 0; p < 4; ++p) {
            int kk = p * 8 + bk0;
            float4 w4 = *reinterpret_cast<const float4*>(&W[(size_t)(k0 + kk) * N + n0 + bn4]);
            sB[(bn4 + 0) * 40 + kk] = f2b(w4.x);
            sB[(bn4 + 1) * 40 + kk] = f2b(w4.y);
            sB[(bn4 + 2) * 40 + kk] = f2b(w4.z);
            sB[(bn4 + 3) * 40 + kk] = f2b(w4.w);
        }
        __syncthreads();
        short8 af[4], bfr[4];
#pragma unroll
        for (int f = 0; f < 4; ++f) {
            af[f]  = *reinterpret_cast<const short8*>(&sA[(wm * 64 + f * 16 + rl) * 40 + hi * 8]);
            bfr[f] = *reinterpret_cast<const short8*>(&sB[(wn * 64 + f * 16 + rl) * 40 + hi * 8]);
        }
#pragma unroll
        for (int i = 0; i < 4; ++i)
#pragma unroll
            for (int j = 0; j < 4; ++j)
                mfma16(acc[i][j], af[i], bfr[j]);
        __syncthreads();
    }
    accfence();
#pragma unroll
    for (int j = 0; j < 4; ++j) {
        const int col = n0 + wn * 64 + j * 16 + rl;
        const float bv = bias[col];
#pragma unroll
        for (int i = 0; i < 4; ++i) {
#pragma unroll
            for (int e = 0; e < 4; ++e) {
                const int row = m0 + wm * 64 + i * 16 + hi * 4 + e;
                float v = acc[i][j][e] + bv;
                if (EPI == 0) {
                    ((float*)Out)[(size_t)row * N + col] = v;
                } else if (EPI == 1) {
                    float gl = 0.5f * v * (1.0f + erff(v * 0.70710678118f));
                    ((short*)Out)[(size_t)row * N + col] = f2b(gl);
                } else {
                    const int b = row >> 9, s = row & 511, nh = col >> 6, d = col & 63;
                    if (EPI == 2)
                        ((short*)Out)[(((size_t)(b * NHEADS + nh) * SEQL + s) << 6) + d] = f2b(v * 0.125f);
                    else if (EPI == 3)
                        ((short*)Out)[(((size_t)(b * NHEADS + nh) * SEQL + s) << 6) + d] = f2b(v);
                    else
                        ((short*)Out)[(((size_t)(b * NHEADS + nh) * DHEAD + d) << 9) + s] = f2b(v);
                }
            }
        }
    }
}

// ---------------- attention: 8-wave blocks, block = (b, h, 32-query-rows) ----------------
// Wave w owns 64 K-cols in QK^T (fn<4); PV splits by (row-half rh = w>>2, d-block db = w&3).
// 32 waves/CU during the latency-bound gather phases (was 16 at 4-wave).
__global__ __launch_bounds__(512) void attn_k(
    const short* __restrict__ qkv, const short* __restrict__ vt,
    const int* __restrict__ mask, short* __restrict__ ctx)
{
    __shared__ short sQ[32 * 72];
    __shared__ short sP[32 * 520];
    __shared__ float wreds[256];

    const int orig = blockIdx.x;
    const int blk = (orig & 7) * (gridDim.x >> 3) + (orig >> 3);
    const int qb = blk & 15, bh = blk >> 4;
    const int b = bh / NHEADS, h = bh % NHEADS;
    const int tid = threadIdx.x, lane = tid & 63, wave = tid >> 6;   // wave 0..7
    const int rl = lane & 15, hi = lane >> 4;
    const short* __restrict__ qh = qkv + (size_t)(b * SEQL) * QKVW + h * 64;
    const short* __restrict__ kh = qh + 768;
    const short* __restrict__ vh = vt + (size_t)bh * DHEAD * SEQL;

    if (tid < 256) {
        int row = tid >> 3, c8 = (tid & 7) << 3;
        *reinterpret_cast<short8*>(&sQ[row * 72 + c8]) =
            *reinterpret_cast<const short8*>(&qh[(size_t)(qb * 32 + row) * QKVW + c8]);
    }

    // mask bias for this wave's 64 K-cols (issued before MFMA: latency hides under QK^T)
    float mb[4];
#pragma unroll
    for (int fn = 0; fn < 4; ++fn) {
        int n = wave * 64 + fn * 16 + rl;
        mb[fn] = -10000.0f * (1.0f - (float)mask[b * SEQL + n]);
    }
    __syncthreads();

    // QK^T: wave covers cols [wave*64, wave*64+64), both 16-row halves
    f32x4 sacc[2][4];
#pragma unroll
    for (int mf = 0; mf < 2; ++mf)
#pragma unroll
        for (int fn = 0; fn < 4; ++fn)
            sacc[mf][fn] = (f32x4){0.f, 0.f, 0.f, 0.f};
    __builtin_amdgcn_s_setprio(1);
#pragma unroll
    for (int ks = 0; ks < 2; ++ks) {
        short8 a0 = *reinterpret_cast<const short8*>(&sQ[rl * 72 + ks * 32 + hi * 8]);
        short8 a1 = *reinterpret_cast<const short8*>(&sQ[(16 + rl) * 72 + ks * 32 + hi * 8]);
#pragma unroll
        for (int fn = 0; fn < 4; ++fn) {
            int n = wave * 64 + fn * 16 + rl;
            short8 bk = *reinterpret_cast<const short8*>(&kh[(size_t)n * QKVW + ks * 32 + hi * 8]);
            mfma16(sacc[0][fn], a0, bk);
            mfma16(sacc[1][fn], a1, bk);
        }
    }
    __builtin_amdgcn_s_setprio(0);
    accfence();

    // exp (no max pass) + bf16 probs to LDS + f32 row partial sums
    float rsum[2][4] = {{0.f, 0.f, 0.f, 0.f}, {0.f, 0.f, 0.f, 0.f}};
#pragma unroll
    for (int mf = 0; mf < 2; ++mf)
#pragma unroll
        for (int fn = 0; fn < 4; ++fn)
#pragma unroll
            for (int e = 0; e < 4; ++e) {
                float p = __expf(sacc[mf][fn][e] + mb[fn]);
                rsum[mf][e] += p;
                sP[(mf * 16 + hi * 4 + e) * 520 + wave * 64 + fn * 16 + rl] = f2b(p);
            }
#pragma unroll
    for (int d = 1; d < 16; d <<= 1)
#pragma unroll
        for (int mf = 0; mf < 2; ++mf)
#pragma unroll
            for (int e = 0; e < 4; ++e)
                rsum[mf][e] += __shfl_xor(rsum[mf][e], d);
    if (rl == 0) {
#pragma unroll
        for (int mf = 0; mf < 2; ++mf)
#pragma unroll
            for (int e = 0; e < 4; ++e)
                wreds[wave * 32 + mf * 16 + hi * 4 + e] = rsum[mf][e];
    }
    __syncthreads();   // sP + wreds visible
    float rsf[2][4];
#pragma unroll
    for (int mf = 0; mf < 2; ++mf)
#pragma unroll
        for (int e = 0; e < 4; ++e) {
            const int row = mf * 16 + hi * 4 + e;
            float s0 = wreds[row]       + wreds[32 + row];
            float s1 = wreds[64 + row]  + wreds[96 + row];
            float s2 = wreds[128 + row] + wreds[160 + row];
            float s3 = wreds[192 + row] + wreds[224 + row];
            rsf[mf][e] = (s0 + s1) + (s2 + s3);
        }

    // PV: wave = (rh = wave>>2 row-half, db = wave&3 d-block of 16)
    const int rh = wave >> 2, db = wave & 3;
    f32x4 oacc = (f32x4){0.f, 0.f, 0.f, 0.f};
    __builtin_amdgcn_s_setprio(1);
#pragma unroll
    for (int ks = 0; ks < 16; ++ks) {
        short8 p  = *reinterpret_cast<const short8*>(&sP[(rh * 16 + rl) * 520 + ks * 32 + hi * 8]);
        short8 bv = *reinterpret_cast<const short8*>(&vh[(size_t)(db * 16 + rl) * SEQL + ks * 32 + hi * 8]);
        mfma16(oacc, p, bv);
    }
    __builtin_amdgcn_s_setprio(0);
    accfence();
#pragma unroll
    for (int e = 0; e < 4; ++e) {
        const int row = rh * 16 + hi * 4 + e;
        const int s = qb * 32 + row;
        const int d = db * 16 + rl;
        float o = oacc[e] * __builtin_amdgcn_rcpf(rsf[rh][e]);
        ctx[((size_t)(b * SEQL + s)) * HID + h * DHEAD + d] = f2b(o);
    }
}

// ---------------- host ----------------
extern "C" void kernel_launch(void* const* d_in, const int* in_sizes, int n_in,
                              void* d_out, int out_size, void* d_ws, size_t ws_size,
                              hipStream_t stream)
{
    const int*   ids  = (const int*)d_in[0];
    const int*   msk  = (const int*)d_in[1];
    const int*   tti  = (const int*)d_in[2];
    const float* tokE = (const float*)d_in[3];
    const float* posE = (const float*)d_in[4];
    const float* typE = (const float*)d_in[5];
    const float* elg  = (const float*)d_in[6];
    const float* elb  = (const float*)d_in[7];
    const float* Wq   = (const float*)d_in[8];  const float* bq = (const float*)d_in[9];
    const float* Wk   = (const float*)d_in[10]; const float* bk = (const float*)d_in[11];
    const float* Wv   = (const float*)d_in[12]; const float* bv = (const float*)d_in[13];
    const float* Wo   = (const float*)d_in[14]; const float* bo = (const float*)d_in[15];
    const float* g1   = (const float*)d_in[16]; const float* b1 = (const float*)d_in[17];
    const float* Wi   = (const float*)d_in[18]; const float* bi = (const float*)d_in[19];
    const float* Wd   = (const float*)d_in[20]; const float* bd = (const float*)d_in[21];
    const float* g2   = (const float*)d_in[22]; const float* b2 = (const float*)d_in[23];

    if (ws_size < 81788928u) return;
    char* ws = (char*)d_ws;
    float* x    = (float*)(ws);
    short* yb   = (short*)(ws + 12582912);
    short* ppb  = (short*)(ws + 18874368);
    short* vt   = (short*)(ws + 18874368);
    short* xb   = (short*)(ws + 25165824);
    short* qkv  = (short*)(ws + 31457280);
    short* ctx  = (short*)(ws + 50331648);
    short* f1   = (short*)(ws + 56623104);
    short* pp3  = (short*)(ws + 50331648);   // FFN2 partial 2 (ctx dead by then)
    short* pp4  = (short*)(ws + 31457280);   // FFN2 partial 3 (qkv dead by then)
    float* y    = (float*)(ws + 12582912);
    short* qq   = (short*)(ws + 31457280);
    short* kk_  = (short*)(ws + 37748736);
    short* vv   = (short*)(ws + 44040192);

    const bool fast = ws_size >= 251768832u;
    embed_ln_k<<<NTOK, 256, 0, stream>>>(ids, tti, tokE, posE, typE, elg, elb,
                                         fast ? nullptr : x, xb);

    if (fast) {
        short* qkvT = (short*)(ws + 81788928);
        short* woT  = (short*)(ws + 124256256);
        short* wiT  = (short*)(ws + 138412032);
        short* wdT  = (short*)(ws + 195035136);
        float* bqkv = (float*)(ws + 251658240);

        wconv_k<<<dim3(12, 12, NLAY), 256, 0, stream>>>(Wq, qkvT, 768, 768, 2304 * 768, 0, 0.125f);
        wconv_k<<<dim3(12, 12, NLAY), 256, 0, stream>>>(Wk, qkvT, 768, 768, 2304 * 768, 768, 1.0f);
        wconv_k<<<dim3(12, 12, NLAY), 256, 0, stream>>>(Wv, qkvT, 768, 768, 2304 * 768, 1536, 1.0f);
        wconv_k<<<dim3(12, 12, NLAY), 256, 0, stream>>>(Wo, woT, 768, 768, 768 * 768, 0, 1.0f);
        wconv_k<<<dim3(12, 48, NLAY), 256, 0, stream>>>(Wi, wiT, 768, 3072, 3072 * 768, 0, 1.0f);
        wconv_k<<<dim3(48, 12, NLAY), 256, 0, stream>>>(Wd, wdT, 3072, 768, 768 * 3072, 0, 1.0f);
        bpack_k<<<108, 256, 0, stream>>>(bq, bk, bv, bqkv);

        for (int l = 0; l < NLAY; ++l) {
            const size_t oH = (size_t)l * HID, oI = (size_t)l * IMID;
            gemm3_k<5><<<dim3(576, 1), 512, 0, stream>>>(xb, qkvT + (size_t)l * 2304 * 768,
                                                         bqkv + (size_t)l * 2304, qkv, 768, 2304, 768,
                                                         vt, nullptr, nullptr);
            attn_k<<<1536, 512, 0, stream>>>(qkv, vt, msk, ctx);
            gemm3_k<6><<<dim3(192, 2), 512, 0, stream>>>(ctx, woT + (size_t)l * 768 * 768,
                                                         bo + oH, yb, 768, 768, 384,
                                                         ppb, nullptr, nullptr);
            add_ln_red_k<<<NTOK, 256, 0, stream>>>(yb, ppb, xb, g1 + oH, b1 + oH, xb, nullptr);
            gemm3_k<1><<<dim3(768, 1), 512, 0, stream>>>(xb, wiT + (size_t)l * 3072 * 768,
                                                         bi + oI, f1, 768, 3072, 768,
                                                         nullptr, nullptr, nullptr);
            gemm3_k<6><<<dim3(192, 4), 512, 0, stream>>>(f1, wdT + (size_t)l * 768 * 3072,
                                                         bd + oH, yb, 3072, 768, 768,
                                                         ppb, pp3, pp4);
            add_ln_red4_k<<<NTOK, 256, 0, stream>>>(yb, ppb, pp3, pp4, xb, g2 + oH, b2 + oH, xb,
                                                    (l == NLAY - 1) ? (float*)d_out : nullptr);
        }
    } else {
        const dim3 g6(32, 6), g24(32, 24);
        for (int l = 0; l < NLAY; ++l) {
            const size_t oHH = (size_t)l * HID * HID, oH = (size_t)l * HID;
            const size_t oHI = (size_t)l * HID * IMID, oI = (size_t)l * IMID;
            gemm_k<2><<<g6, 256, 0, stream>>>(xb, Wq + oHH, bq + oH, qq, HID, HID);
            gemm_k<3><<<g6, 256, 0, stream>>>(xb, Wk + oHH, bk + oH, kk_, HID, HID);
            gemm_k<4><<<g6, 256, 0, stream>>>(xb, Wv + oHH, bv + oH, vv, HID, HID);
            attn_k<<<1536, 512, 0, stream>>>(qq, vv, msk, ctx);
            gemm_k<0><<<g6, 256, 0, stream>>>(ctx, Wo + oHH, bo + oH, y, HID, HID);
            add_ln_k<<<NTOK, 256, 0, stream>>>(y, x, g1 + oH, b1 + oH, x, xb, nullptr);
            gemm_k<1><<<g24, 256, 0, stream>>>(xb, Wi + oHI, bi + oI, f1, HID, IMID);
            gemm_k<0><<<g6, 256, 0, stream>>>(f1, Wd + oHI, bd + oH, y, IMID, HID);
            add_ln_k<<<NTOK, 256, 0, stream>>>(y, x, g2 + oH, b2 + oH, x, xb,
                                               (l == NLAY - 1) ? (float*)d_out : nullptr);
        }
    }
}

// Round 15
// 2038.422 us; speedup vs baseline: 1.0471x; 1.0471x over previous
//
#include <hip/hip_runtime.h>
#include <math.h>

#define NHEADS 12
#define DHEAD  64
#define SEQL   512
#define HID    768
#define IMID   3072
#define NTOK   4096
#define NLAY   12
#define QKVW   2304

typedef __attribute__((ext_vector_type(8))) short short8;
typedef __attribute__((ext_vector_type(4))) float f32x4;

__device__ __forceinline__ short f2b(float f) {
    union { float f; unsigned u; } v; v.f = f;
    unsigned r = (v.u + 0x7fffu + ((v.u >> 16) & 1u)) >> 16;
    return (short)r;
}
__device__ __forceinline__ float b2f(short h) {
    union { unsigned u; float f; } v; v.u = ((unsigned)(unsigned short)h) << 16;
    return v.f;
}
__device__ __forceinline__ void mfma16(f32x4& c, short8 a, short8 b) {
    asm volatile("v_mfma_f32_16x16x32_bf16 %0, %1, %2, %0" : "+v"(c) : "v"(a), "v"(b));
}
__device__ __forceinline__ void accfence() {
    __builtin_amdgcn_sched_barrier(0);
    asm volatile("s_nop 7\ns_nop 7\ns_nop 7\ns_nop 7");
    __builtin_amdgcn_sched_barrier(0);
}
__device__ __forceinline__ void gload_lds16(const void* g, void* l) {
    __builtin_amdgcn_global_load_lds(
        (const __attribute__((address_space(1))) unsigned int*)g,
        (__attribute__((address_space(3))) unsigned int*)l, 16, 0, 0);
}
// exact-GELU via A&S 7.1.26 erf approx (|eps|<1.5e-7, << bf16 ulp)
__device__ __forceinline__ float gelu_f(float v) {
    float x = v * 0.70710678118f;
    float ax = fabsf(x);
    float t = 1.0f / (1.0f + 0.3275911f * ax);
    float p = ((((1.061405429f * t - 1.453152027f) * t) + 1.421413741f) * t
               - 0.284496736f) * t + 0.254829592f;
    float e = p * t * __expf(-x * x);
    float er = 1.0f - e;
    er = x < 0.f ? -er : er;
    return 0.5f * v * (1.0f + er);
}

// ---------------- weight convert+transpose: W f32 [K,N] -> WT bf16 [N,K] (x scale) ----------------
__global__ __launch_bounds__(256) void wconv_k(
    const float* __restrict__ src, short* __restrict__ dst,
    int K, int N, size_t dlsz, int rowStart, float scale)
{
    __shared__ short t[64][72];
    src += (size_t)blockIdx.z * K * N;
    dst += (size_t)blockIdx.z * dlsz;
    const int k0 = blockIdx.x * 64, n0 = blockIdx.y * 64;
    const int kr = threadIdx.x >> 2, q = threadIdx.x & 3;
    const float* s = src + (size_t)(k0 + kr) * N + n0 + q * 16;
#pragma unroll
    for (int j = 0; j < 16; j += 4) {
        float4 v = *reinterpret_cast<const float4*>(s + j);
        t[q * 16 + j + 0][kr] = f2b(v.x * scale);
        t[q * 16 + j + 1][kr] = f2b(v.y * scale);
        t[q * 16 + j + 2][kr] = f2b(v.z * scale);
        t[q * 16 + j + 3][kr] = f2b(v.w * scale);
    }
    __syncthreads();
    const int r = threadIdx.x >> 2;
    short* d = dst + (size_t)(rowStart + n0 + r) * K + k0 + q * 16;
    *reinterpret_cast<short8*>(d)     = *reinterpret_cast<short8*>(&t[r][q * 16]);
    *reinterpret_cast<short8*>(d + 8) = *reinterpret_cast<short8*>(&t[r][q * 16 + 8]);
}

__global__ __launch_bounds__(256) void bpack_k(
    const float* __restrict__ bq, const float* __restrict__ bk,
    const float* __restrict__ bv, float* __restrict__ dst)
{
    int i = blockIdx.x * 256 + threadIdx.x;
    if (i >= NLAY * QKVW) return;
    int l = i / QKVW, c = i % QKVW;
    float v = c < 768 ? 0.125f * bq[l * 768 + c]
            : c < 1536 ? bk[l * 768 + c - 768] : bv[l * 768 + c - 1536];
    dst[i] = v;
}

// ---------------- embeddings + LN ----------------
__global__ __launch_bounds__(256) void embed_ln_k(
    const int* __restrict__ ids, const int* __restrict__ tti,
    const float* __restrict__ tokE, const float* __restrict__ posE,
    const float* __restrict__ typE, const float* __restrict__ g,
    const float* __restrict__ bb, float* __restrict__ x, short* __restrict__ xb)
{
    __shared__ float red[8];
    const int t = blockIdx.x, s = t & (SEQL - 1);
    const int id = ids[t], ty = tti[t];
    float v[3], sum = 0.f, sq = 0.f;
#pragma unroll
    for (int i = 0; i < 3; ++i) {
        const int c = threadIdx.x + 256 * i;
        float e = tokE[(size_t)id * HID + c] + typE[(size_t)ty * HID + c]
                + posE[(size_t)s * HID + c];
        v[i] = e; sum += e; sq += e * e;
    }
#pragma unroll
    for (int d = 1; d < 64; d <<= 1) { sum += __shfl_xor(sum, d); sq += __shfl_xor(sq, d); }
    const int lane = threadIdx.x & 63, w = threadIdx.x >> 6;
    if (lane == 0) { red[w] = sum; red[4 + w] = sq; }
    __syncthreads();
    sum = red[0] + red[1] + red[2] + red[3];
    sq  = red[4] + red[5] + red[6] + red[7];
    const float mu = sum * (1.0f / 768.0f);
    const float var = sq * (1.0f / 768.0f) - mu * mu;
    const float rstd = rsqrtf(var + 1e-3f);
#pragma unroll
    for (int i = 0; i < 3; ++i) {
        const int c = threadIdx.x + 256 * i;
        float yv = (v[i] - mu) * rstd * g[c] + bb[c];
        if (x) x[(size_t)t * HID + c] = yv;
        xb[(size_t)t * HID + c] = f2b(yv);
    }
}

// ---------------- residual add + LN (legacy, fallback path) ----------------
__global__ __launch_bounds__(256) void add_ln_k(
    const float* __restrict__ y, const float* __restrict__ res,
    const float* __restrict__ g, const float* __restrict__ bb,
    float* __restrict__ xout, short* __restrict__ bout, float* __restrict__ fout)
{
    __shared__ float red[8];
    const int t = blockIdx.x;
    float v[3], sum = 0.f, sq = 0.f;
#pragma unroll
    for (int i = 0; i < 3; ++i) {
        const int c = threadIdx.x + 256 * i;
        float e = y[(size_t)t * HID + c] + res[(size_t)t * HID + c];
        v[i] = e; sum += e; sq += e * e;
    }
#pragma unroll
    for (int d = 1; d < 64; d <<= 1) { sum += __shfl_xor(sum, d); sq += __shfl_xor(sq, d); }
    const int lane = threadIdx.x & 63, w = threadIdx.x >> 6;
    if (lane == 0) { red[w] = sum; red[4 + w] = sq; }
    __syncthreads();
    sum = red[0] + red[1] + red[2] + red[3];
    sq  = red[4] + red[5] + red[6] + red[7];
    const float mu = sum * (1.0f / 768.0f);
    const float var = sq * (1.0f / 768.0f) - mu * mu;
    const float rstd = rsqrtf(var + 1e-3f);
#pragma unroll
    for (int i = 0; i < 3; ++i) {
        const int c = threadIdx.x + 256 * i;
        float yv = (v[i] - mu) * rstd * g[c] + bb[c];
        xout[(size_t)t * HID + c] = yv;
        bout[(size_t)t * HID + c] = f2b(yv);
        if (fout) fout[(size_t)t * HID + c] = yv;
    }
}

// ---------------- split-K(2) bf16 partials + bf16 residual + LN -> bf16 stream ----------------
// Residual carried in bf16 (== GEMM-input rounding already in the datapath).
// In-place res==bout is safe: rows partitioned per block, same-thread read-before-write.
__global__ __launch_bounds__(256) void add_ln_red_k(
    const short* __restrict__ p0, const short* __restrict__ p1,
    const short* __restrict__ res, const float* __restrict__ g,
    const float* __restrict__ bb, short* __restrict__ bout, float* __restrict__ fout)
{
    __shared__ float red[8];
    const int t = blockIdx.x;
    float v[3], sum = 0.f, sq = 0.f;
#pragma unroll
    for (int i = 0; i < 3; ++i) {
        const int c = threadIdx.x + 256 * i;
        const size_t o = (size_t)t * HID + c;
        float e = b2f(p0[o]) + b2f(p1[o]) + b2f(res[o]);
        v[i] = e; sum += e; sq += e * e;
    }
#pragma unroll
    for (int d = 1; d < 64; d <<= 1) { sum += __shfl_xor(sum, d); sq += __shfl_xor(sq, d); }
    const int lane = threadIdx.x & 63, w = threadIdx.x >> 6;
    if (lane == 0) { red[w] = sum; red[4 + w] = sq; }
    __syncthreads();
    sum = red[0] + red[1] + red[2] + red[3];
    sq  = red[4] + red[5] + red[6] + red[7];
    const float mu = sum * (1.0f / 768.0f);
    const float var = sq * (1.0f / 768.0f) - mu * mu;
    const float rstd = rsqrtf(var + 1e-3f);
#pragma unroll
    for (int i = 0; i < 3; ++i) {
        const int c = threadIdx.x + 256 * i;
        float yv = (v[i] - mu) * rstd * g[c] + bb[c];
        bout[(size_t)t * HID + c] = f2b(yv);
        if (fout) fout[(size_t)t * HID + c] = yv;
    }
}

// ---------------- pipelined GEMM, 8-wave blocks: C[4096,N] = A[M,K] @ WT[N,K]^T ----------------
// 128x128 tile, 512 threads, 3-buffer LDS, depth-2 counted vmcnt.
// EPI 0 = f32+bias; 1 = GELU bf16 (fast erf); 5 = QKV: Q,K linear bf16; V tiles (n0>=1536)
//   transposed in reclaimed staging LDS -> Out2 = vt [b,nh,d,s]; 6 = split-K bf16 partial
template<int EPI>
__global__ __launch_bounds__(512, 4) void gemm3_k(
    const short* __restrict__ A, const short* __restrict__ Wt,
    const float* __restrict__ bias, void* __restrict__ Out, int K, int N, int kChunk,
    void* __restrict__ Out2)
{
    __shared__ short sA[3][128 * 32];
    __shared__ short sB[3][128 * 32];
    const int tid = threadIdx.x;
    const int lane = tid & 63, wave = tid >> 6;
    const int wm = wave >> 1, wn = wave & 1;
    const int rl = lane & 15, hi = lane >> 4;

    const int nb = gridDim.x, bid = blockIdx.x;
    const int id = (bid & 7) * (nb >> 3) + (bid >> 3);
    const int m0 = (id & 31) * 128, n0 = (id >> 5) * 128;
    const int kBeg = blockIdx.y * kChunk;

    f32x4 acc[2][4];
#pragma unroll
    for (int i = 0; i < 2; ++i)
#pragma unroll
        for (int j = 0; j < 4; ++j)
            acc[i][j] = (f32x4){0.f, 0.f, 0.f, 0.f};

    auto stage = [&](int buf, int k0) {
        const int gb = wave * 64;
        const int gid = gb + lane;
        const int row = gid >> 2, sg = gid & 3;
        const int ksw = (sg ^ ((row >> 1) & 3)) << 3;
        gload_lds16(&A[(size_t)(m0 + row) * K + k0 + ksw], &sA[buf][gb * 8]);
        gload_lds16(&Wt[(size_t)(n0 + row) * K + k0 + ksw], &sB[buf][gb * 8]);
    };

    const int nIter = kChunk >> 5;
    stage(0, kBeg);
    if (nIter > 1) stage(1, kBeg + 32);
    for (int t = 0; t < nIter; ++t) {
        const int cur = t % 3;
        if (t + 2 < nIter) {
            stage((t + 2) % 3, kBeg + (t + 2) * 32);
            __builtin_amdgcn_sched_barrier(0);
            asm volatile("s_waitcnt vmcnt(4)" ::: "memory");
        } else if (t + 1 < nIter) {
            __builtin_amdgcn_sched_barrier(0);
            asm volatile("s_waitcnt vmcnt(2)" ::: "memory");
        } else {
            __builtin_amdgcn_sched_barrier(0);
            asm volatile("s_waitcnt vmcnt(0)" ::: "memory");
        }
        __builtin_amdgcn_s_barrier();
        __builtin_amdgcn_sched_barrier(0);

        short8 af[2], bfr[4];
#pragma unroll
        for (int f = 0; f < 2; ++f) {
            const int ra = wm * 32 + f * 16 + rl;
            af[f] = *reinterpret_cast<const short8*>(&sA[cur][ra * 32 + ((hi ^ ((ra >> 1) & 3)) << 3)]);
        }
#pragma unroll
        for (int j = 0; j < 4; ++j) {
            const int rb = wn * 64 + j * 16 + rl;
            bfr[j] = *reinterpret_cast<const short8*>(&sB[cur][rb * 32 + ((hi ^ ((rb >> 1) & 3)) << 3)]);
        }
#pragma unroll
        for (int i = 0; i < 2; ++i)
#pragma unroll
            for (int j = 0; j < 4; ++j)
                mfma16(acc[i][j], af[i], bfr[j]);

        asm volatile("s_waitcnt lgkmcnt(0)" ::: "memory");
        __builtin_amdgcn_sched_barrier(0);
        __builtin_amdgcn_s_barrier();
    }
    accfence();

    if (EPI == 5 && n0 >= 1536) {
        short* tl = (short*)&sA[0][0];
        const int b = m0 >> 9, s0 = m0 & 511;
        const int vbase = n0 - 1536;
        const int c = tid >> 2, rq = (tid & 3) << 4;
        const int vcol = vbase + c;
        short* dstRow = (short*)Out2 +
            (((size_t)(b * NHEADS + (vcol >> 6)) * DHEAD + (vcol & 63)) << 9) + s0;
#pragma unroll
        for (int pass = 0; pass < 2; ++pass) {
            if ((wm >> 1) == pass) {
#pragma unroll
                for (int j = 0; j < 4; ++j) {
                    const int cc = wn * 64 + j * 16 + rl;
                    const float bv = bias[n0 + cc];
#pragma unroll
                    for (int i = 0; i < 2; ++i)
#pragma unroll
                        for (int e = 0; e < 4; ++e) {
                            const int r = (wm & 1) * 32 + i * 16 + hi * 4 + e;
                            tl[cc * 68 + r] = f2b(acc[i][j][e] + bv);
                        }
                }
            }
            __builtin_amdgcn_s_barrier();
            *reinterpret_cast<short8*>(dstRow + pass * 64 + rq) =
                *reinterpret_cast<short8*>(&tl[c * 68 + rq]);
            *reinterpret_cast<short8*>(dstRow + pass * 64 + rq + 8) =
                *reinterpret_cast<short8*>(&tl[c * 68 + rq + 8]);
            __builtin_amdgcn_s_barrier();
        }
        return;
    }

    short* skDst = nullptr;
    if (EPI == 6)
        skDst = blockIdx.y == 0 ? (short*)Out : (short*)Out2;
#pragma unroll
    for (int j = 0; j < 4; ++j) {
        const int col = n0 + wn * 64 + j * 16 + rl;
        const float bv = (EPI == 6 && blockIdx.y != 0) ? 0.f : bias[col];
#pragma unroll
        for (int i = 0; i < 2; ++i) {
#pragma unroll
            for (int e = 0; e < 4; ++e) {
                const int row = m0 + wm * 32 + i * 16 + hi * 4 + e;
                float v = acc[i][j][e] + bv;
                if (EPI == 0) {
                    ((float*)Out)[(size_t)row * N + col] = v;
                } else if (EPI == 1) {
                    ((short*)Out)[(size_t)row * N + col] = f2b(gelu_f(v));
                } else if (EPI == 6) {
                    skDst[(size_t)row * N + col] = f2b(v);
                } else {
                    ((short*)Out)[(size_t)row * N + col] = f2b(v);
                }
            }
        }
    }
}

// ---------------- legacy GEMM (fallback path): W f32 [K,N] ----------------
template<int EPI>
__global__ __launch_bounds__(256) void gemm_k(
    const short* __restrict__ A, const float* __restrict__ W,
    const float* __restrict__ bias, void* __restrict__ Out, int K, int N)
{
    __shared__ short sA[128 * 40];
    __shared__ short sB[128 * 40];
    const int tid = threadIdx.x;
    const int lane = tid & 63, wave = tid >> 6;
    const int wm = wave >> 1, wn = wave & 1;
    const int m0 = blockIdx.x * 128, n0 = blockIdx.y * 128;
    const int rl = lane & 15, hi = lane >> 4;

    f32x4 acc[4][4];
#pragma unroll
    for (int i = 0; i < 4; ++i)
#pragma unroll
        for (int j = 0; j < 4; ++j)
            acc[i][j] = (f32x4){0.f, 0.f, 0.f, 0.f};

    const int arow = tid >> 2, ac8 = (tid & 3) << 3;
    const int bk0 = tid >> 5, bn4 = (tid & 31) << 2;

    for (int k0 = 0; k0 < K; k0 += 32) {
#pragma unroll
        for (int i = 0; i < 2; ++i) {
            int row = i * 64 + arow;
            short8 v = *reinterpret_cast<const short8*>(&A[(size_t)(m0 + row) * K + k0 + ac8]);
            *reinterpret_cast<short8*>(&sA[row * 40 + ac8]) = v;
        }
#pragma unroll
        for (int p = 0; p < 4; ++p) {
            int kk = p * 8 + bk0;
            float4 w4 = *reinterpret_cast<const float4*>(&W[(size_t)(k0 + kk) * N + n0 + bn4]);
            sB[(bn4 + 0) * 40 + kk] = f2b(w4.x);
            sB[(bn4 + 1) * 40 + kk] = f2b(w4.y);
            sB[(bn4 + 2) * 40 + kk] = f2b(w4.z);
            sB[(bn4 + 3) * 40 + kk] = f2b(w4.w);
        }
        __syncthreads();
        short8 af[4], bfr[4];
#pragma unroll
        for (int f = 0; f < 4; ++f) {
            af[f]  = *reinterpret_cast<const short8*>(&sA[(wm * 64 + f * 16 + rl) * 40 + hi * 8]);
            bfr[f] = *reinterpret_cast<const short8*>(&sB[(wn * 64 + f * 16 + rl) * 40 + hi * 8]);
        }
#pragma unroll
        for (int i = 0; i < 4; ++i)
#pragma unroll
            for (int j = 0; j < 4; ++j)
                mfma16(acc[i][j], af[i], bfr[j]);
        __syncthreads();
    }
    accfence();
#pragma unroll
    for (int j = 0; j < 4; ++j) {
        const int col = n0 + wn * 64 + j * 16 + rl;
        const float bv = bias[col];
#pragma unroll
        for (int i = 0; i < 4; ++i) {
#pragma unroll
            for (int e = 0; e < 4; ++e) {
                const int row = m0 + wm * 64 + i * 16 + hi * 4 + e;
                float v = acc[i][j][e] + bv;
                if (EPI == 0) {
                    ((float*)Out)[(size_t)row * N + col] = v;
                } else if (EPI == 1) {
                    float gl = 0.5f * v * (1.0f + erff(v * 0.70710678118f));
                    ((short*)Out)[(size_t)row * N + col] = f2b(gl);
                } else {
                    const int b = row >> 9, s = row & 511, nh = col >> 6, d = col & 63;
                    if (EPI == 2)
                        ((short*)Out)[(((size_t)(b * NHEADS + nh) * SEQL + s) << 6) + d] = f2b(v * 0.125f);
                    else if (EPI == 3)
                        ((short*)Out)[(((size_t)(b * NHEADS + nh) * SEQL + s) << 6) + d] = f2b(v);
                    else
                        ((short*)Out)[(((size_t)(b * NHEADS + nh) * DHEAD + d) << 9) + s] = f2b(v);
                }
            }
        }
    }
}

// ---------------- attention: 4-wave blocks, block = (b, h, 32-query-rows); no-max softmax ----------------
__global__ __launch_bounds__(256) void attn_k(
    const short* __restrict__ qkv, const short* __restrict__ vt,
    const int* __restrict__ mask, short* __restrict__ ctx)
{
    __shared__ short sQ[32 * 72];
    __shared__ short sP[32 * 520];
    __shared__ float wreds[128];

    const int orig = blockIdx.x;
    const int blk = (orig & 7) * (gridDim.x >> 3) + (orig >> 3);
    const int qb = blk & 15, bh = blk >> 4;
    const int b = bh / NHEADS, h = bh % NHEADS;
    const int tid = threadIdx.x, lane = tid & 63, wave = tid >> 6;
    const int rl = lane & 15, hi = lane >> 4;
    const short* __restrict__ qh = qkv + (size_t)(b * SEQL) * QKVW + h * 64;
    const short* __restrict__ kh = qh + 768;
    const short* __restrict__ vh = vt + (size_t)bh * DHEAD * SEQL;

    {
        int row = tid >> 3, c8 = (tid & 7) << 3;
        *reinterpret_cast<short8*>(&sQ[row * 72 + c8]) =
            *reinterpret_cast<const short8*>(&qh[(size_t)(qb * 32 + row) * QKVW + c8]);
    }

    float mb[8];
#pragma unroll
    for (int fn = 0; fn < 8; ++fn) {
        int n = wave * 128 + fn * 16 + rl;
        mb[fn] = -10000.0f * (1.0f - (float)mask[b * SEQL + n]);
    }
    __syncthreads();

    f32x4 sacc[2][8];
#pragma unroll
    for (int mf = 0; mf < 2; ++mf)
#pragma unroll
        for (int fn = 0; fn < 8; ++fn)
            sacc[mf][fn] = (f32x4){0.f, 0.f, 0.f, 0.f};
    __builtin_amdgcn_s_setprio(1);
#pragma unroll
    for (int ks = 0; ks < 2; ++ks) {
        short8 a0 = *reinterpret_cast<const short8*>(&sQ[rl * 72 + ks * 32 + hi * 8]);
        short8 a1 = *reinterpret_cast<const short8*>(&sQ[(16 + rl) * 72 + ks * 32 + hi * 8]);
#pragma unroll
        for (int fn = 0; fn < 8; ++fn) {
            int n = wave * 128 + fn * 16 + rl;
            short8 bk = *reinterpret_cast<const short8*>(&kh[(size_t)n * QKVW + ks * 32 + hi * 8]);
            mfma16(sacc[0][fn], a0, bk);
            mfma16(sacc[1][fn], a1, bk);
        }
    }
    __builtin_amdgcn_s_setprio(0);
    accfence();

    float rsum[2][4] = {{0.f, 0.f, 0.f, 0.f}, {0.f, 0.f, 0.f, 0.f}};
#pragma unroll
    for (int mf = 0; mf < 2; ++mf)
#pragma unroll
        for (int fn = 0; fn < 8; ++fn)
#pragma unroll
            for (int e = 0; e < 4; ++e) {
                float p = __expf(sacc[mf][fn][e] + mb[fn]);
                rsum[mf][e] += p;
                sP[(mf * 16 + hi * 4 + e) * 520 + wave * 128 + fn * 16 + rl] = f2b(p);
            }
#pragma unroll
    for (int d = 1; d < 16; d <<= 1)
#pragma unroll
        for (int mf = 0; mf < 2; ++mf)
#pragma unroll
            for (int e = 0; e < 4; ++e)
                rsum[mf][e] += __shfl_xor(rsum[mf][e], d);
    if (rl == 0) {
#pragma unroll
        for (int mf = 0; mf < 2; ++mf)
#pragma unroll
            for (int e = 0; e < 4; ++e)
                wreds[wave * 32 + mf * 16 + hi * 4 + e] = rsum[mf][e];
    }
    __syncthreads();
    float rsf[2][4];
#pragma unroll
    for (int mf = 0; mf < 2; ++mf)
#pragma unroll
        for (int e = 0; e < 4; ++e) {
            const int row = mf * 16 + hi * 4 + e;
            rsf[mf][e] = wreds[row] + wreds[32 + row] + wreds[64 + row] + wreds[96 + row];
        }

    f32x4 oacc[2];
    oacc[0] = (f32x4){0.f, 0.f, 0.f, 0.f};
    oacc[1] = (f32x4){0.f, 0.f, 0.f, 0.f};
    __builtin_amdgcn_s_setprio(1);
#pragma unroll
    for (int ks = 0; ks < 16; ++ks) {
        short8 p0 = *reinterpret_cast<const short8*>(&sP[rl * 520 + ks * 32 + hi * 8]);
        short8 p1 = *reinterpret_cast<const short8*>(&sP[(16 + rl) * 520 + ks * 32 + hi * 8]);
        short8 bv = *reinterpret_cast<const short8*>(&vh[(size_t)(wave * 16 + rl) * SEQL + ks * 32 + hi * 8]);
        mfma16(oacc[0], p0, bv);
        mfma16(oacc[1], p1, bv);
    }
    __builtin_amdgcn_s_setprio(0);
    accfence();
#pragma unroll
    for (int mf = 0; mf < 2; ++mf) {
#pragma unroll
        for (int e = 0; e < 4; ++e) {
            const int row = mf * 16 + hi * 4 + e;
            const int s = qb * 32 + row;
            const int d = wave * 16 + rl;
            float o = oacc[mf][e] * __builtin_amdgcn_rcpf(rsf[mf][e]);
            ctx[((size_t)(b * SEQL + s)) * HID + h * DHEAD + d] = f2b(o);
        }
    }
}

// ---------------- host ----------------
extern "C" void kernel_launch(void* const* d_in, const int* in_sizes, int n_in,
                              void* d_out, int out_size, void* d_ws, size_t ws_size,
                              hipStream_t stream)
{
    const int*   ids  = (const int*)d_in[0];
    const int*   msk  = (const int*)d_in[1];
    const int*   tti  = (const int*)d_in[2];
    const float* tokE = (const float*)d_in[3];
    const float* posE = (const float*)d_in[4];
    const float* typE = (const float*)d_in[5];
    const float* elg  = (const float*)d_in[6];
    const float* elb  = (const float*)d_in[7];
    const float* Wq   = (const float*)d_in[8];  const float* bq = (const float*)d_in[9];
    const float* Wk   = (const float*)d_in[10]; const float* bk = (const float*)d_in[11];
    const float* Wv   = (const float*)d_in[12]; const float* bv = (const float*)d_in[13];
    const float* Wo   = (const float*)d_in[14]; const float* bo = (const float*)d_in[15];
    const float* g1   = (const float*)d_in[16]; const float* b1 = (const float*)d_in[17];
    const float* Wi   = (const float*)d_in[18]; const float* bi = (const float*)d_in[19];
    const float* Wd   = (const float*)d_in[20]; const float* bd = (const float*)d_in[21];
    const float* g2   = (const float*)d_in[22]; const float* b2 = (const float*)d_in[23];

    if (ws_size < 81788928u) return;
    char* ws = (char*)d_ws;
    float* x    = (float*)(ws);
    short* yb   = (short*)(ws + 12582912);
    short* ppb  = (short*)(ws + 18874368);
    short* vt   = (short*)(ws + 18874368);
    short* xb   = (short*)(ws + 25165824);
    short* qkv  = (short*)(ws + 31457280);
    short* ctx  = (short*)(ws + 50331648);
    short* f1   = (short*)(ws + 56623104);
    float* y    = (float*)(ws + 12582912);
    short* qq   = (short*)(ws + 31457280);
    short* kk_  = (short*)(ws + 37748736);
    short* vv   = (short*)(ws + 44040192);

    const bool fast = ws_size >= 251768832u;
    embed_ln_k<<<NTOK, 256, 0, stream>>>(ids, tti, tokE, posE, typE, elg, elb,
                                         fast ? nullptr : x, xb);

    if (fast) {
        short* qkvT = (short*)(ws + 81788928);
        short* woT  = (short*)(ws + 124256256);
        short* wiT  = (short*)(ws + 138412032);
        short* wdT  = (short*)(ws + 195035136);
        float* bqkv = (float*)(ws + 251658240);

        wconv_k<<<dim3(12, 12, NLAY), 256, 0, stream>>>(Wq, qkvT, 768, 768, 2304 * 768, 0, 0.125f);
        wconv_k<<<dim3(12, 12, NLAY), 256, 0, stream>>>(Wk, qkvT, 768, 768, 2304 * 768, 768, 1.0f);
        wconv_k<<<dim3(12, 12, NLAY), 256, 0, stream>>>(Wv, qkvT, 768, 768, 2304 * 768, 1536, 1.0f);
        wconv_k<<<dim3(12, 12, NLAY), 256, 0, stream>>>(Wo, woT, 768, 768, 768 * 768, 0, 1.0f);
        wconv_k<<<dim3(12, 48, NLAY), 256, 0, stream>>>(Wi, wiT, 768, 3072, 3072 * 768, 0, 1.0f);
        wconv_k<<<dim3(48, 12, NLAY), 256, 0, stream>>>(Wd, wdT, 3072, 768, 768 * 3072, 0, 1.0f);
        bpack_k<<<108, 256, 0, stream>>>(bq, bk, bv, bqkv);

        for (int l = 0; l < NLAY; ++l) {
            const size_t oH = (size_t)l * HID, oI = (size_t)l * IMID;
            gemm3_k<5><<<dim3(576, 1), 512, 0, stream>>>(xb, qkvT + (size_t)l * 2304 * 768,
                                                         bqkv + (size_t)l * 2304, qkv, 768, 2304, 768,
                                                         vt);
            attn_k<<<1536, 256, 0, stream>>>(qkv, vt, msk, ctx);
            gemm3_k<6><<<dim3(192, 2), 512, 0, stream>>>(ctx, woT + (size_t)l * 768 * 768,
                                                         bo + oH, yb, 768, 768, 384, ppb);
            add_ln_red_k<<<NTOK, 256, 0, stream>>>(yb, ppb, xb, g1 + oH, b1 + oH, xb, nullptr);
            gemm3_k<1><<<dim3(768, 1), 512, 0, stream>>>(xb, wiT + (size_t)l * 3072 * 768,
                                                         bi + oI, f1, 768, 3072, 768,
                                                         nullptr);
            gemm3_k<6><<<dim3(192, 2), 512, 0, stream>>>(f1, wdT + (size_t)l * 768 * 3072,
                                                         bd + oH, yb, 3072, 768, 1536, ppb);
            add_ln_red_k<<<NTOK, 256, 0, stream>>>(yb, ppb, xb, g2 + oH, b2 + oH, xb,
                                                   (l == NLAY - 1) ? (float*)d_out : nullptr);
        }
    } else {
        const dim3 g6(32, 6), g24(32, 24);
        for (int l = 0; l < NLAY; ++l) {
            const size_t oHH = (size_t)l * HID * HID, oH = (size_t)l * HID;
            const size_t oHI = (size_t)l * HID * IMID, oI = (size_t)l * IMID;
            gemm_k<2><<<g6, 256, 0, stream>>>(xb, Wq + oHH, bq + oH, qq, HID, HID);
            gemm_k<3><<<g6, 256, 0, stream>>>(xb, Wk + oHH, bk + oH, kk_, HID, HID);
            gemm_k<4><<<g6, 256, 0, stream>>>(xb, Wv + oHH, bv + oH, vv, HID, HID);
            attn_k<<<1536, 256, 0, stream>>>(qq, vv, msk, ctx);
            gemm_k<0><<<g6, 256, 0, stream>>>(ctx, Wo + oHH, bo + oH, y, HID, HID);
            add_ln_k<<<NTOK, 256, 0, stream>>>(y, x, g1 + oH, b1 + oH, x, xb, nullptr);
            gemm_k<1><<<g24, 256, 0, stream>>>(xb, Wi + oHI, bi + oI, f1, HID, IMID);
            gemm_k<0><<<g6, 256, 0, stream>>>(f1, Wd + oHI, bd + oH, y, IMID, HID);
            add_ln_k<<<NTOK, 256, 0, stream>>>(y, x, g2 + oH, b2 + oH, x, xb,
                                               (l == NLAY - 1) ? (float*)d_out : nullptr);
        }
    }
}